// Round 1
// baseline (43.088 us; speedup 1.0000x reference)
//
#include <hip/hip_runtime.h>

// UnitaryQuantizer: masked elementwise phase quantization.
// out[b][r][c] = (r + c <= N-2) ? quant(x[b][r][c]) : 0
// N = 512, B = 128, f32 in/out. Pure streaming, memory-bound.

#define N_DIM 512

__global__ __launch_bounds__(256) void UnitaryQuantizer_kernel(
    const float* __restrict__ x, float* __restrict__ out, int n4)
{
    // Constants computed in double (matching numpy's np.pi math) then cast to f32,
    // exactly as the reference does before jnp casts to float32.
    constexpr double PI_D   = 3.14159265358979323846;
    constexpr float TWO_PI  = (float)(2.0 * PI_D);
    constexpr float INV_2PI = (float)(1.0 / (2.0 * PI_D));
    constexpr float THR     = (float)(1.5 * PI_D);                 // wrap threshold
    constexpr float PMIN    = (float)((0.015625 - 0.5) * PI_D);    // (0.5^6 - 0.5)*pi
    constexpr float PMAX    = (float)((1.5 - 0.0078125) * PI_D);   // (1.5 - 0.5^7)*pi
    constexpr float RATIO   = (float)((((1.5 - 0.0078125) * PI_D) -
                                       ((0.015625 - 0.5) * PI_D)) / 255.0);

    const int stride = gridDim.x * blockDim.x;
    for (int t = blockIdx.x * blockDim.x + threadIdx.x; t < n4; t += stride) {
        const int e = t << 2;              // linear element index of lane's float4
        const int r = (e >> 9) & (N_DIM - 1);
        const int c = e & (N_DIM - 1);     // cols c..c+3, all same row (512 % 4 == 0)

        const float4 v = reinterpret_cast<const float4*>(x)[t];
        float in[4]  = {v.x, v.y, v.z, v.w};
        float res[4];

        #pragma unroll
        for (int j = 0; j < 4; ++j) {
            float m = in[j];
            // mod 2pi (floor-based; exact identity for m in [0, 2pi))
            m = m - TWO_PI * floorf(m * INV_2PI);
            // wrap (pi*1.5, 2pi) -> negative
            if (m > THR) m -= TWO_PI;
            // clip
            m = fminf(fmaxf(m, PMIN), PMAX);
            // quantize to 255 steps, round-half-even like jnp.round
            float q = rintf((m - PMIN) / RATIO) * RATIO + PMIN;
            // mask: only strict-upper-triangle-mapped positions survive
            res[j] = ((r + c + j) <= (N_DIM - 2)) ? q : 0.0f;
        }

        float4 o = {res[0], res[1], res[2], res[3]};
        reinterpret_cast<float4*>(out)[t] = o;
    }
}

extern "C" void kernel_launch(void* const* d_in, const int* in_sizes, int n_in,
                              void* d_out, int out_size, void* d_ws, size_t ws_size,
                              hipStream_t stream) {
    const float* x = (const float*)d_in[0];
    float* out = (float*)d_out;
    const int n  = in_sizes[0];     // 128*512*512 = 33,554,432
    const int n4 = n >> 2;          // float4 count

    const int block = 256;
    const int grid  = 2048;         // ~8 blocks/CU, grid-stride the rest
    UnitaryQuantizer_kernel<<<grid, block, 0, stream>>>(x, out, n4);
}

// Round 3
// 38.147 us; speedup vs baseline: 1.1295x; 1.1295x over previous
//
#include <hip/hip_runtime.h>

// UnitaryQuantizer: masked elementwise phase quantization.
// out[b][r][c] = (r + c <= N-2) ? quant(x[b][r][c]) : 0
// N = 512, B = 128, f32 in/out. Memory-bound.
//
// Key insight: masked positions don't need their input read at all.
// Per row r only the prefix c in [0, 510-r] is live (~50% of input).
// Predicated loads skip the rest; non-temporal stores keep the live
// input cache-resident across replays.

#define N_DIM 512

typedef float floatx4 __attribute__((ext_vector_type(4)));  // native vector for nt-store

__global__ __launch_bounds__(256) void UnitaryQuantizer_kernel(
    const float* __restrict__ x, float* __restrict__ out, int n4)
{
    constexpr double PI_D   = 3.14159265358979323846;
    constexpr float TWO_PI  = (float)(2.0 * PI_D);
    constexpr float INV_2PI = (float)(1.0 / (2.0 * PI_D));
    constexpr float THR     = (float)(1.5 * PI_D);                 // wrap threshold
    constexpr float PMIN    = (float)((0.015625 - 0.5) * PI_D);    // (0.5^6 - 0.5)*pi
    constexpr float PMAX    = (float)((1.5 - 0.0078125) * PI_D);   // (1.5 - 0.5^7)*pi
    constexpr float RATIO   = (float)((((1.5 - 0.0078125) * PI_D) -
                                       ((0.015625 - 0.5) * PI_D)) / 255.0);

    const floatx4* __restrict__ x4 = reinterpret_cast<const floatx4*>(x);
    floatx4* __restrict__ o4 = reinterpret_cast<floatx4*>(out);

    const int stride = gridDim.x * blockDim.x;
    for (int t = blockIdx.x * blockDim.x + threadIdx.x; t < n4; t += stride) {
        const int e = t << 2;              // linear element index of lane's float4
        const int r = (e >> 9) & (N_DIM - 1);
        const int c = e & (N_DIM - 1);     // cols c..c+3, same row (512 % 4 == 0)

        floatx4 o = {0.0f, 0.0f, 0.0f, 0.0f};

        if (r + c <= N_DIM - 2) {          // at least one live element -> load
            const floatx4 v = x4[t];
            #pragma unroll
            for (int j = 0; j < 4; ++j) {
                float m = v[j];
                // mod 2pi (floor-based; exact identity for m in [0, 2pi))
                m = m - TWO_PI * floorf(m * INV_2PI);
                // wrap (1.5pi, 2pi) -> negative
                if (m > THR) m -= TWO_PI;
                // clip
                m = fminf(fmaxf(m, PMIN), PMAX);
                // quantize to 255 steps, round-half-even like jnp.round
                float q = rintf((m - PMIN) / RATIO) * RATIO + PMIN;
                // per-element mask at the diagonal boundary
                o[j] = ((r + c + j) <= (N_DIM - 2)) ? q : 0.0f;
            }
        }

        // Non-temporal: don't let output evict the (re-read) input from L2/L3.
        __builtin_nontemporal_store(o, &o4[t]);
    }
}

extern "C" void kernel_launch(void* const* d_in, const int* in_sizes, int n_in,
                              void* d_out, int out_size, void* d_ws, size_t ws_size,
                              hipStream_t stream) {
    const float* x = (const float*)d_in[0];
    float* out = (float*)d_out;
    const int n  = in_sizes[0];     // 128*512*512 = 33,554,432
    const int n4 = n >> 2;          // float4 count

    const int block = 256;
    const int grid  = 2048;         // ~8 blocks/CU, grid-stride the rest
    UnitaryQuantizer_kernel<<<grid, block, 0, stream>>>(x, out, n4);
}

// Round 4
// 36.155 us; speedup vs baseline: 1.1918x; 1.0551x over previous
//
#include <hip/hip_runtime.h>

// UnitaryQuantizer: masked elementwise phase quantization.
// out[b][r][c] = (r + c <= N-2) ? quant(x[b][r][c]) : 0
// N = 512, B = 128, f32 in/out. Memory-bound.
//
// Predicated loads: masked positions (r+c > 510, ~half the tensor) never
// read their input -> ~67 MB of the 134 MB input skipped.
// Plain cached stores: live input + output = 201 MB fits the 256 MB L3,
// and nt-stores measurably degraded write-path efficiency (R3: 5.3 TB/s
// effective vs 6.2 for the cached path in R0).

#define N_DIM 512

typedef float floatx4 __attribute__((ext_vector_type(4)));

__global__ __launch_bounds__(256) void UnitaryQuantizer_kernel(
    const float* __restrict__ x, float* __restrict__ out, int n4)
{
    constexpr double PI_D   = 3.14159265358979323846;
    constexpr float TWO_PI  = (float)(2.0 * PI_D);
    constexpr float INV_2PI = (float)(1.0 / (2.0 * PI_D));
    constexpr float THR     = (float)(1.5 * PI_D);                 // wrap threshold
    constexpr float PMIN    = (float)((0.015625 - 0.5) * PI_D);    // (0.5^6 - 0.5)*pi
    constexpr float PMAX    = (float)((1.5 - 0.0078125) * PI_D);   // (1.5 - 0.5^7)*pi
    constexpr float RATIO   = (float)((((1.5 - 0.0078125) * PI_D) -
                                       ((0.015625 - 0.5) * PI_D)) / 255.0);

    const floatx4* __restrict__ x4 = reinterpret_cast<const floatx4*>(x);
    floatx4* __restrict__ o4 = reinterpret_cast<floatx4*>(out);

    const int stride = gridDim.x * blockDim.x;
    for (int t = blockIdx.x * blockDim.x + threadIdx.x; t < n4; t += stride) {
        const int e = t << 2;              // linear element index of lane's float4
        const int r = (e >> 9) & (N_DIM - 1);
        const int c = e & (N_DIM - 1);     // cols c..c+3, same row (512 % 4 == 0)

        floatx4 o = {0.0f, 0.0f, 0.0f, 0.0f};

        if (r + c <= N_DIM - 2) {          // at least one live element -> load
            const floatx4 v = x4[t];
            #pragma unroll
            for (int j = 0; j < 4; ++j) {
                float m = v[j];
                // mod 2pi (floor-based; exact identity for m in [0, 2pi))
                m = m - TWO_PI * floorf(m * INV_2PI);
                // wrap (1.5pi, 2pi) -> negative
                if (m > THR) m -= TWO_PI;
                // clip
                m = fminf(fmaxf(m, PMIN), PMAX);
                // quantize to 255 steps, round-half-even like jnp.round
                float q = rintf((m - PMIN) / RATIO) * RATIO + PMIN;
                // per-element mask at the diagonal boundary
                o[j] = ((r + c + j) <= (N_DIM - 2)) ? q : 0.0f;
            }
        }

        o4[t] = o;                         // plain cached dwordx4 store
    }
}

extern "C" void kernel_launch(void* const* d_in, const int* in_sizes, int n_in,
                              void* d_out, int out_size, void* d_ws, size_t ws_size,
                              hipStream_t stream) {
    const float* x = (const float*)d_in[0];
    float* out = (float*)d_out;
    const int n  = in_sizes[0];     // 128*512*512 = 33,554,432
    const int n4 = n >> 2;          // float4 count

    const int block = 256;
    const int grid  = 2048;         // ~8 blocks/CU, grid-stride the rest
    UnitaryQuantizer_kernel<<<grid, block, 0, stream>>>(x, out, n4);
}